// Round 3
// baseline (4805.222 us; speedup 1.0000x reference)
//
#include <hip/hip_runtime.h>

#define B_ 8
#define N_ 32768
#define S_ 1024
#define C_ 96
#define T_ 1024            // ONE block per batch: 16 waves on ONE CU, LDS-only sync
#define W_ (T_ / 64)       // 16 waves per block
#define PPT (N_ / T_)      // 32 points per thread
#define PK (PPT / 2)       // 16 float2 pairs per thread

typedef float f2v __attribute__((ext_vector_type(2)));
typedef unsigned long long u64;
typedef unsigned int u32;

// Round 3: the inter-block key exchange is DELETED. Rounds 0-2 showed the
// per-step cost was ~6700 cy of agent-scope (sc1) round trips (7.1 GB of
// line-billed FETCH), and both attempts at an XCD-local L2 transport hung:
// r1 = atomic-RMW poll storm serializing at the TCC; r2 = plain stores
// write-allocating dirty slot lines in one XCD's L2 that, on eviction,
// clobber agent-scope keys from other XCDs (mixed-scope stores to a shared
// line are unsound on non-coherent L2s). This version has NO inter-block
// dependencies at all: one 1024-thread block owns a whole batch.
//   - coords + running min-dists for all 32K points in registers
//     (32 pts/thread = 128 VGPRs; 4 waves/SIMD, cap 512/wave -> no spill)
//   - per step: per-thread argmax -> 6-level wave butterfly -> 1 LDS slot
//     per wave -> ONE __syncthreads -> 16-key read + 4-level butterfly.
//   - LDS buffer double-buffered by step parity: one barrier per step is
//     sufficient (read@s precedes barrier@s+1 precedes write@s+2).
// Key = (float_bits(dist) << 32) | ~idx : u64-max == (max dist, min idx),
// exactly the reference argmax tie-break (first index of the max).

// d_out layout (float32, concatenated):
//   [0, B*S*3)                      new_xyz  (B,S,3)
//   [B*S*3, B*S*3+B*C*S)            new_fea  (B,C,S)
//   [B*S*3+B*C*S, +B*S)             indices  (B,S) as float

__global__ __launch_bounds__(T_)
__attribute__((amdgpu_waves_per_eu(4, 4)))   // 16 waves / 4 SIMDs -> 512-VGPR budget
void fps_kernel(
    const float* __restrict__ xyz,   // (B, N, 3)
    float* __restrict__ out)
{
#pragma clang fp contract(off)
  const int b    = blockIdx.x;       // one block per batch
  const int t    = threadIdx.x;
  const int lane = t & 63;
  const int w    = t >> 6;
  const float* xb = xyz + (size_t)b * N_ * 3;

  float* out_xyz = out;
  float* out_idx = out + (size_t)B_*S_*3 + (size_t)B_*C_*S_;

  __shared__ u64 red[2][W_];         // per-wave winner keys, parity double-buffered

  // Coords AND running min-dists fully in registers (96 + 32 VGPRs).
  // Thread t owns points g = j*T_ + t, j = 0..31 (g strictly increasing in j
  // -> per-thread first-max scan picks the thread's smallest global index).
  f2v X[PK], Y[PK], Z[PK], D[PK];
  #pragma unroll
  for (int k = 0; k < PK; ++k) {
    const int g0 = (2*k)   * T_ + t;
    const int g1 = (2*k+1) * T_ + t;
    X[k] = (f2v){xb[g0*3+0], xb[g1*3+0]};
    Y[k] = (f2v){xb[g0*3+1], xb[g1*3+1]};
    Z[k] = (f2v){xb[g0*3+2], xb[g1*3+2]};
    D[k] = (f2v){1e10f, 1e10f};
  }
  #pragma unroll
  for (int k = 0; k < PK; ++k) {
    asm volatile("" : "+v"(X[k]), "+v"(Y[k]), "+v"(Z[k]));  // not rematerializable
  }

  int cur = 0;
  for (int s = 0; s < S_; ++s) {
    const int cu = __builtin_amdgcn_readfirstlane(cur);   // uniform -> scalar loads
    const float cx = xb[cu*3+0];
    const float cy = xb[cu*3+1];
    const float cz = xb[cu*3+2];
    if (t == 0) {
      out_idx[(size_t)b*S_ + s] = (float)cu;
      float* o = out_xyz + ((size_t)b*S_ + s)*3;
      o[0] = cx; o[1] = cy; o[2] = cz;
    }
    const f2v c2x = (f2v){cx, cx};
    const f2v c2y = (f2v){cy, cy};
    const f2v c2z = (f2v){cz, cz};

    // Exact IEEE ((dx^2+dy^2)+dz^2), no contraction; per-thread argmax with
    // first-index tie-break (ascending j, strict >; idx(j0) < idx(j1) in pair).
    float bv = -1.0f;
    int   bj = 0;
    #pragma unroll
    for (int k = 0; k < PK; ++k) {
      const f2v dx = X[k] - c2x;
      const f2v dy = Y[k] - c2y;
      const f2v dz = Z[k] - c2z;
      const f2v d  = (dx*dx + dy*dy) + dz*dz;
      f2v nd;
      nd.x = fminf(D[k].x, d.x);
      nd.y = fminf(D[k].y, d.y);
      D[k] = nd;
      if (nd.x > bv) { bv = nd.x; bj = 2*k;   }
      if (nd.y > bv) { bv = nd.y; bj = 2*k+1; }
    }
    const int bg = (bj << 10) + t;             // global point index (T_ == 1024)

    // Pack and butterfly-max across the wave: all lanes end with wave key.
    u64 key = ((u64)__float_as_uint(bv) << 32) | (u32)(~bg);
    #pragma unroll
    for (int off = 32; off > 0; off >>= 1) {
      const u64 ok = __shfl_xor(key, off);
      if (ok > key) key = ok;
    }

    // Cross-wave reduce: one LDS slot per wave, ONE barrier, local combine.
    if (lane == 0) red[s & 1][w] = key;
    __syncthreads();
    u64 k = red[s & 1][lane & (W_ - 1)];       // 16 keys, broadcast across groups
    #pragma unroll
    for (int off = 8; off > 0; off >>= 1) {    // reduce within each 16-lane group
      const u64 ok = __shfl_xor(k, off);
      if (ok > k) k = ok;
    }
    cur = (int)(u32)(~(u32)k);                 // decode winner index
  }
}

__global__ void gather_fea_kernel(
    const float* __restrict__ feat,   // (B, C, N)
    const float* __restrict__ idxf,   // (B, S) float indices (in d_out)
    float* __restrict__ out_fea)      // (B, C, S)
{
  const int t = blockIdx.x * blockDim.x + threadIdx.x;
  if (t >= B_ * C_ * S_) return;
  const int s  = t & (S_ - 1);
  const int bc = t >> 10;           // S_ == 1024
  const int c  = bc % C_;
  const int b  = bc / C_;
  const int idx = (int)idxf[(size_t)b * S_ + s];
  out_fea[t] = feat[((size_t)b * C_ + c) * (size_t)N_ + idx];
}

extern "C" void kernel_launch(void* const* d_in, const int* in_sizes, int n_in,
                              void* d_out, int out_size, void* d_ws, size_t ws_size,
                              hipStream_t stream) {
  const float* xyz  = (const float*)d_in[0];   // (B,N,3)
  const float* feat = (const float*)d_in[1];   // (B,C,N)
  float* out = (float*)d_out;

  float* out_fea = out + (size_t)B_ * S_ * 3;
  float* out_idx = out + (size_t)B_ * S_ * 3 + (size_t)B_ * C_ * S_;
  (void)d_ws; (void)ws_size; (void)in_sizes; (void)n_in; (void)out_size;

  fps_kernel<<<B_, T_, 0, stream>>>(xyz, out);

  const int total = B_ * C_ * S_;
  gather_fea_kernel<<<(total + 255) / 256, 256, 0, stream>>>(feat, out_idx, out_fea);
}

// Round 4
// 3633.184 us; speedup vs baseline: 1.3226x; 1.3226x over previous
//
#include <hip/hip_runtime.h>

#define B_ 8
#define N_ 32768
#define S_ 1024
#define C_ 96
#define T_ 512             // ONE block per batch: 8 waves on one CU, LDS-only sync
#define W_ (T_ / 64)       // 8 waves per block
#define PPT (N_ / T_)      // 64 points per thread
#define PK (PPT / 2)       // 32 float2 pairs per thread (coords in regs)
#define PQ (PPT / 4)       // 16 float4 quads per thread (min-dists in LDS)

typedef float f2v __attribute__((ext_vector_type(2)));
typedef float f4v __attribute__((ext_vector_type(4)));
typedef unsigned long long u64;
typedef unsigned int u32;

// Round 4: same sync-free structure as round 3 (one block per batch, barrier-
// only, hang-impossible) but with the residency fixed. Round 3's counters
// (VGPR_Count=64, FETCH 1.97 GB / WRITE 0.96 GB on a 12 MB input) showed the
// whole point state spilled to scratch: 16 waves under waves_per_eu(4,4) gave
// a 128-VGPR budget vs ~160 needed. A batch's full state (32K pts x 4 floats
// = 128K floats) equals the ENTIRE CU register file, so it cannot all live in
// VGPRs. Split it:
//   - coords X,Y,Z: 192 VGPRs/thread (T=512 -> 2 waves/SIMD -> 256 budget)
//   - running min-dists D: LDS float4[16][512] = 128 KB (<= 160 KB/CU),
//     Dl[q][t] is 16B/lane contiguous -> conflict-free b128, 256 KB/step.
// Per step: per-thread argmax over 64 pts -> 6-lvl wave butterfly -> 1 LDS
// slot/wave -> ONE __syncthreads -> 8-key read + 3-lvl butterfly. Key =
// (float_bits(dist)<<32) | ~idx : u64-max == (max dist, min idx) == the
// reference argmax first-index tie-break.

// d_out layout (float32, concatenated):
//   [0, B*S*3)                      new_xyz  (B,S,3)
//   [B*S*3, B*S*3+B*C*S)            new_fea  (B,C,S)
//   [B*S*3+B*C*S, +B*S)             indices  (B,S) as float

__global__ __launch_bounds__(T_)
__attribute__((amdgpu_waves_per_eu(2, 2)))   // 8 waves = 2/SIMD -> 256-VGPR budget
void fps_kernel(
    const float* __restrict__ xyz,   // (B, N, 3)
    float* __restrict__ out)
{
#pragma clang fp contract(off)
  const int b    = blockIdx.x;       // one block per batch
  const int t    = threadIdx.x;
  const int lane = t & 63;
  const int w    = t >> 6;
  const float* xb = xyz + (size_t)b * N_ * 3;

  float* out_xyz = out;
  float* out_idx = out + (size_t)B_*S_*3 + (size_t)B_*C_*S_;

  __shared__ f4v Dl[PQ][T_];         // 128 KB running min-dists
  __shared__ u64 red[2][W_];         // per-wave winner keys, parity dbuf

  // Coords in registers (192 VGPRs). Thread t owns points g = j*T_ + t,
  // j = 0..63 ascending -> per-thread first-max scan == smallest index.
  f2v X[PK], Y[PK], Z[PK];
  #pragma unroll
  for (int k = 0; k < PK; ++k) {
    const int g0 = (2*k)   * T_ + t;
    const int g1 = (2*k+1) * T_ + t;
    X[k] = (f2v){xb[g0*3+0], xb[g1*3+0]};
    Y[k] = (f2v){xb[g0*3+1], xb[g1*3+1]};
    Z[k] = (f2v){xb[g0*3+2], xb[g1*3+2]};
  }
  #pragma unroll
  for (int k = 0; k < PK; ++k) {
    asm volatile("" : "+v"(X[k]), "+v"(Y[k]), "+v"(Z[k]));  // not rematerializable
  }

  #pragma unroll
  for (int q = 0; q < PQ; ++q) {
    Dl[q][t] = (f4v){1e10f, 1e10f, 1e10f, 1e10f};
  }
  __syncthreads();

  int cur = 0;
  for (int s = 0; s < S_; ++s) {
    const int cu = __builtin_amdgcn_readfirstlane(cur);   // uniform -> scalar loads
    const float cx = xb[cu*3+0];
    const float cy = xb[cu*3+1];
    const float cz = xb[cu*3+2];
    if (t == 0) {
      out_idx[(size_t)b*S_ + s] = (float)cu;
      float* o = out_xyz + ((size_t)b*S_ + s)*3;
      o[0] = cx; o[1] = cy; o[2] = cz;
    }
    const f2v c2x = (f2v){cx, cx};
    const f2v c2y = (f2v){cy, cy};
    const f2v c2z = (f2v){cz, cz};

    // Exact IEEE ((dx^2+dy^2)+dz^2), no contraction (verbatim from the
    // proven kernel); per-thread argmax, first-index tie-break (ascending j,
    // strict >). Quad q covers j = 4q..4q+3 via coord pairs 2q, 2q+1.
    float bv = -1.0f;
    int   bj = 0;
    #pragma unroll
    for (int q = 0; q < PQ; ++q) {
      const f4v dq = Dl[q][t];                 // ds_read_b128, conflict-free
      const f2v dx0 = X[2*q]   - c2x;
      const f2v dy0 = Y[2*q]   - c2y;
      const f2v dz0 = Z[2*q]   - c2z;
      const f2v d0  = (dx0*dx0 + dy0*dy0) + dz0*dz0;
      const f2v dx1 = X[2*q+1] - c2x;
      const f2v dy1 = Y[2*q+1] - c2y;
      const f2v dz1 = Z[2*q+1] - c2z;
      const f2v d1  = (dx1*dx1 + dy1*dy1) + dz1*dz1;
      f4v nd;
      nd.x = fminf(dq.x, d0.x);
      nd.y = fminf(dq.y, d0.y);
      nd.z = fminf(dq.z, d1.x);
      nd.w = fminf(dq.w, d1.y);
      Dl[q][t] = nd;                           // ds_write_b128, conflict-free
      if (nd.x > bv) { bv = nd.x; bj = 4*q;   }
      if (nd.y > bv) { bv = nd.y; bj = 4*q+1; }
      if (nd.z > bv) { bv = nd.z; bj = 4*q+2; }
      if (nd.w > bv) { bv = nd.w; bj = 4*q+3; }
    }
    const int bg = (bj << 9) + t;              // global point index (T_ == 512)

    // Pack and butterfly-max across the wave: all lanes end with wave key.
    u64 key = ((u64)__float_as_uint(bv) << 32) | (u32)(~bg);
    #pragma unroll
    for (int off = 32; off > 0; off >>= 1) {
      const u64 ok = __shfl_xor(key, off);
      if (ok > key) key = ok;
    }

    // Cross-wave reduce: one LDS slot per wave, ONE barrier, local combine.
    if (lane == 0) red[s & 1][w] = key;
    __syncthreads();
    u64 k = red[s & 1][lane & (W_ - 1)];       // 8 keys, broadcast across groups
    #pragma unroll
    for (int off = W_ / 2; off > 0; off >>= 1) {   // reduce within 8-lane groups
      const u64 ok = __shfl_xor(k, off);
      if (ok > k) k = ok;
    }
    cur = (int)(u32)(~(u32)k);                 // decode winner index
  }
}

__global__ void gather_fea_kernel(
    const float* __restrict__ feat,   // (B, C, N)
    const float* __restrict__ idxf,   // (B, S) float indices (in d_out)
    float* __restrict__ out_fea)      // (B, C, S)
{
  const int t = blockIdx.x * blockDim.x + threadIdx.x;
  if (t >= B_ * C_ * S_) return;
  const int s  = t & (S_ - 1);
  const int bc = t >> 10;           // S_ == 1024
  const int c  = bc % C_;
  const int b  = bc / C_;
  const int idx = (int)idxf[(size_t)b * S_ + s];
  out_fea[t] = feat[((size_t)b * C_ + c) * (size_t)N_ + idx];
}

extern "C" void kernel_launch(void* const* d_in, const int* in_sizes, int n_in,
                              void* d_out, int out_size, void* d_ws, size_t ws_size,
                              hipStream_t stream) {
  const float* xyz  = (const float*)d_in[0];   // (B,N,3)
  const float* feat = (const float*)d_in[1];   // (B,C,N)
  float* out = (float*)d_out;

  float* out_fea = out + (size_t)B_ * S_ * 3;
  float* out_idx = out + (size_t)B_ * S_ * 3 + (size_t)B_ * C_ * S_;
  (void)d_ws; (void)ws_size; (void)in_sizes; (void)n_in; (void)out_size;

  fps_kernel<<<B_, T_, 0, stream>>>(xyz, out);

  const int total = B_ * C_ * S_;
  gather_fea_kernel<<<(total + 255) / 256, 256, 0, stream>>>(feat, out_idx, out_fea);
}

// Round 5
// 2800.322 us; speedup vs baseline: 1.7160x; 1.2974x over previous
//
#include <hip/hip_runtime.h>

#define B_ 8
#define N_ 32768
#define S_ 1024
#define C_ 96
#define T_ 512             // ONE block per batch: 8 waves on one CU, LDS-only sync
#define W_ (T_ / 64)       // 8 waves per block
#define PPT (N_ / T_)      // 64 points per thread
#define PK (PPT / 2)       // 32 float2 pairs per thread (coords in regs)
#define PQ (PPT / 4)       // 16 float4 quads per thread (min-dists in LDS)

typedef float f2v __attribute__((ext_vector_type(2)));
typedef float f4v __attribute__((ext_vector_type(4)));
typedef unsigned long long u64;
typedef unsigned int u32;

// Round 5: same sync-free one-block-per-batch structure as round 4 (passed,
// 3633 us). Round 4 counters: VGPR=128 (allocator split 256-budget into
// 128 VGPR + 128 AGPR -> accvgpr_read tax on the 192 coord regs), FETCH
// 1.6 MB (scratch gone). Step cost ~8200 cy vs ~2050 cy DS floor. This
// round cuts instruction fat + DS ops, keeps all semantics bit-exact:
//  - lazy quad-argmax: packed min/max + 1 select per quad (was 4 cmp +
//    8 cndmask); element index re-derived once post-loop from one LDS read.
//  - DPP wave reduce (rocPRIM pattern: row_shr 1/2/4/8 + row_bcast 15/31,
//    result in lane 63): value-max then index-min among matching lanes.
//    Replaces the u64 shfl butterfly: -12 ds_bpermute/wave/step, moves
//    reduce onto VALU. (max value, min index) == reference first-argmax.
//  - 2-ahead software pipeline on Dl b128 reads (covers ~120 cy DS latency
//    at 2 waves/SIMD).
// Distance expression (contract off), scan order, and tie-breaks verbatim
// from the proven kernel -> identical winners.

// d_out layout (float32, concatenated):
//   [0, B*S*3)                      new_xyz  (B,S,3)
//   [B*S*3, B*S*3+B*C*S)            new_fea  (B,C,S)
//   [B*S*3+B*C*S, +B*S)             indices  (B,S) as float

// 6-step wave64 DPP reduce steps (valid-source lanes combine, invalid keep old):
#define DPP_FMAX(x, ctrl)                                                   \
  x = fmaxf(x, __int_as_float(__builtin_amdgcn_update_dpp(                  \
          __float_as_int(x), __float_as_int(x), ctrl, 0xf, 0xf, false)))
#define DPP_UMIN(c, ctrl)                                                   \
  {                                                                         \
    const u32 o_ = (u32)__builtin_amdgcn_update_dpp(                        \
        (int)c, (int)c, ctrl, 0xf, 0xf, false);                             \
    c = (o_ < c) ? o_ : c;                                                  \
  }

__global__ __launch_bounds__(T_)
__attribute__((amdgpu_waves_per_eu(2, 2)))   // 8 waves = 2/SIMD -> 256-reg budget
void fps_kernel(
    const float* __restrict__ xyz,   // (B, N, 3)
    float* __restrict__ out)
{
#pragma clang fp contract(off)
  const int b    = blockIdx.x;       // one block per batch
  const int t    = threadIdx.x;
  const int lane = t & 63;
  const int w    = t >> 6;
  const float* xb = xyz + (size_t)b * N_ * 3;

  float* out_xyz = out;
  float* out_idx = out + (size_t)B_*S_*3 + (size_t)B_*C_*S_;

  __shared__ f4v Dl[PQ][T_];         // 128 KB running min-dists
  __shared__ u64 red[2][W_];         // per-wave winner keys, parity dbuf

  // Coords in registers (192 regs). Thread t owns points g = j*T_ + t,
  // j = 0..63 ascending -> first-max scan == smallest index.
  f2v X[PK], Y[PK], Z[PK];
  #pragma unroll
  for (int k = 0; k < PK; ++k) {
    const int g0 = (2*k)   * T_ + t;
    const int g1 = (2*k+1) * T_ + t;
    X[k] = (f2v){xb[g0*3+0], xb[g1*3+0]};
    Y[k] = (f2v){xb[g0*3+1], xb[g1*3+1]};
    Z[k] = (f2v){xb[g0*3+2], xb[g1*3+2]};
  }
  #pragma unroll
  for (int k = 0; k < PK; ++k) {
    asm volatile("" : "+v"(X[k]), "+v"(Y[k]), "+v"(Z[k]));  // not rematerializable
  }

  #pragma unroll
  for (int q = 0; q < PQ; ++q) {
    Dl[q][t] = (f4v){1e10f, 1e10f, 1e10f, 1e10f};
  }
  __syncthreads();

  int cur = 0;
  for (int s = 0; s < S_; ++s) {
    const int cu = __builtin_amdgcn_readfirstlane(cur);   // uniform -> scalar loads
    const float cx = xb[cu*3+0];
    const float cy = xb[cu*3+1];
    const float cz = xb[cu*3+2];
    if (t == 0) {
      out_idx[(size_t)b*S_ + s] = (float)cu;
      float* o = out_xyz + ((size_t)b*S_ + s)*3;
      o[0] = cx; o[1] = cy; o[2] = cz;
    }
    const f2v c2x = (f2v){cx, cx};
    const f2v c2y = (f2v){cy, cy};
    const f2v c2z = (f2v){cz, cz};

    // Exact IEEE ((dx^2+dy^2)+dz^2), no contraction (verbatim). Lazy argmax:
    // track (quad max, first quad) only; element resolved after the loop.
    float bv = -1.0f;
    int   bq = 0;

    // One quad's update: distances for coord pairs 2q,2q+1; packed min into
    // running D; packed quad max; first-quad strict-> select.
    #define UPDATE_QUAD(qc, dq)                                             \
      {                                                                     \
        const f2v dx0 = X[2*(qc)]   - c2x;                                  \
        const f2v dy0 = Y[2*(qc)]   - c2y;                                  \
        const f2v dz0 = Z[2*(qc)]   - c2z;                                  \
        const f2v d0  = (dx0*dx0 + dy0*dy0) + dz0*dz0;                      \
        const f2v dx1 = X[2*(qc)+1] - c2x;                                  \
        const f2v dy1 = Y[2*(qc)+1] - c2y;                                  \
        const f2v dz1 = Z[2*(qc)+1] - c2z;                                  \
        const f2v d1  = (dx1*dx1 + dy1*dy1) + dz1*dz1;                      \
        const f2v nd01 = __builtin_elementwise_min((f2v){dq.x, dq.y}, d0);  \
        const f2v nd23 = __builtin_elementwise_min((f2v){dq.z, dq.w}, d1);  \
        Dl[(qc)][t] = (f4v){nd01.x, nd01.y, nd23.x, nd23.y};                \
        const f2v qm2 = __builtin_elementwise_max(nd01, nd23);              \
        const float qm = fmaxf(qm2.x, qm2.y);                               \
        if (qm > bv) { bv = qm; bq = (qc); }                                \
      }

    // 2-quad groups, next group's b128 reads issued before current compute.
    f4v sA = Dl[0][t];
    f4v sB = Dl[1][t];
    #pragma unroll
    for (int g = 0; g < PQ/2; ++g) {
      const f4v dqA = sA;
      const f4v dqB = sB;
      if (g + 1 < PQ/2) {
        sA = Dl[2*g+2][t];
        sB = Dl[2*g+3][t];
      }
      UPDATE_QUAD(2*g,     dqA);
      UPDATE_QUAD(2*g + 1, dqB);
    }
    #undef UPDATE_QUAD

    // Resolve element within the winning quad (nd stored this step; same
    // bits as the qm chain -> equality guaranteed). Descending priority
    // selects == first (smallest) matching element.
    {
      const f4v nd = Dl[bq][t];
      int e = 3;
      if (nd.z == bv) e = 2;
      if (nd.y == bv) e = 1;
      if (nd.x == bv) e = 0;
      bq = (bq << 2) + e;            // bj: per-thread point ordinal 0..63
    }
    const int bg = (bq << 9) + t;    // global point index (T_ == 512)

    // Wave reduce via DPP (no LDS): value max -> lane 63; then min global
    // index among lanes holding the max. fmax/min return operands exactly,
    // so vmax is bitwise one of the lanes' bv.
    float xv = bv;
    DPP_FMAX(xv, 0x111);             // row_shr:1
    DPP_FMAX(xv, 0x112);             // row_shr:2
    DPP_FMAX(xv, 0x114);             // row_shr:4
    DPP_FMAX(xv, 0x118);             // row_shr:8
    DPP_FMAX(xv, 0x142);             // row_bcast:15
    DPP_FMAX(xv, 0x143);             // row_bcast:31
    const float vmax = __int_as_float(
        __builtin_amdgcn_readlane(__float_as_int(xv), 63));
    u32 c = (bv == vmax) ? (u32)bg : 0xFFFFFFFFu;
    DPP_UMIN(c, 0x111);
    DPP_UMIN(c, 0x112);
    DPP_UMIN(c, 0x114);
    DPP_UMIN(c, 0x118);
    DPP_UMIN(c, 0x142);
    DPP_UMIN(c, 0x143);
    const u32 widx = (u32)__builtin_amdgcn_readlane((int)c, 63);

    // Cross-wave reduce: one LDS slot per wave, ONE barrier, local combine.
    // Key = (bits(vmax)<<32) | ~idx : u64-max == (max dist, min idx).
    const u64 wkey = ((u64)__float_as_uint(vmax) << 32) | (u32)(~widx);
    if (lane == 0) red[s & 1][w] = wkey;
    __syncthreads();
    u64 k = red[s & 1][lane & (W_ - 1)];       // 8 keys, broadcast across groups
    #pragma unroll
    for (int off = W_ / 2; off > 0; off >>= 1) {   // reduce within 8-lane groups
      const u64 ok = __shfl_xor(k, off);
      if (ok > k) k = ok;
    }
    cur = (int)(u32)(~(u32)k);                 // decode winner index
  }
}

__global__ void gather_fea_kernel(
    const float* __restrict__ feat,   // (B, C, N)
    const float* __restrict__ idxf,   // (B, S) float indices (in d_out)
    float* __restrict__ out_fea)      // (B, C, S)
{
  const int t = blockIdx.x * blockDim.x + threadIdx.x;
  if (t >= B_ * C_ * S_) return;
  const int s  = t & (S_ - 1);
  const int bc = t >> 10;           // S_ == 1024
  const int c  = bc % C_;
  const int b  = bc / C_;
  const int idx = (int)idxf[(size_t)b * S_ + s];
  out_fea[t] = feat[((size_t)b * C_ + c) * (size_t)N_ + idx];
}

extern "C" void kernel_launch(void* const* d_in, const int* in_sizes, int n_in,
                              void* d_out, int out_size, void* d_ws, size_t ws_size,
                              hipStream_t stream) {
  const float* xyz  = (const float*)d_in[0];   // (B,N,3)
  const float* feat = (const float*)d_in[1];   // (B,C,N)
  float* out = (float*)d_out;

  float* out_fea = out + (size_t)B_ * S_ * 3;
  float* out_idx = out + (size_t)B_ * S_ * 3 + (size_t)B_ * C_ * S_;
  (void)d_ws; (void)ws_size; (void)in_sizes; (void)n_in; (void)out_size;

  fps_kernel<<<B_, T_, 0, stream>>>(xyz, out);

  const int total = B_ * C_ * S_;
  gather_fea_kernel<<<(total + 255) / 256, 256, 0, stream>>>(feat, out_idx, out_fea);
}